// Round 1
// 199.436 us; speedup vs baseline: 1.0045x; 1.0045x over previous
//
#include <hip/hip_runtime.h>

// RQS (rational-quadratic spline) transform, 8192x2048 f32, K=8 bins.
// R1: 82us, VALU-bound (VALUBusy 66%, HBM 25%), occupancy 28%.
// R3 FAILED: __launch_bounds__(256,8) VGPR cap -> table spills (FETCH 33->295MB).
// R4: (256,4), plain loads/stores, single fast __logf logdet. ~80us kernel.
// R5: replace the 49-op 6-value cndmask select chain with:
//       - cw[9] kept in VGPRs: 7 cmps select icw/ncw AND accumulate bin idx
//       - (ch[k], dv[k]) float2 tables in LDS, gathered via 2x ds_read_b64
//     Cuts per-element VALU ~25% and frees ~36 VGPR/thread of tables.
//     LDS = 512 dims * 9 * 8B = 36,864 B -> 4 blocks/CU -> occupancy ~50%.

constexpr int   KBINS = 8;
constexpr float TAILF = 3.0f;
constexpr float MINW  = 0.001f;
constexpr float MINH  = 0.001f;
constexpr float MIND  = 0.001f;
constexpr int   NROWS = 8192;
constexpr int   NDIM  = 2048;
constexpr int   NPAR  = 3 * KBINS - 1;  // 23
constexpr int   VEC   = 2;              // dims per thread (float2 loads/stores)
constexpr int   BLOCK = 256;
constexpr int   DIMS_PER_BLOCK = BLOCK * VEC;           // 512
constexpr int   BLOCKS_PER_ROW = NDIM / DIMS_PER_BLOCK; // 4
constexpr int   GROWS = 512;                            // parallel row walkers
constexpr int   ROWS_PER_WALK = NROWS / GROWS;          // 16

typedef float v2f __attribute__((ext_vector_type(2)));

__device__ __forceinline__ float rcp_fast(float x) {
    return __builtin_amdgcn_rcpf(x);  // v_rcp_f32, ~1 ulp
}

// fast softplus: max(x,0) + log(1+exp(-|x|)) with v_exp/v_log
__device__ __forceinline__ float softplus_fast(float x) {
    return fmaxf(x, 0.0f) + __logf(1.0f + __expf(-fabsf(x)));
}

// Evaluate one element. cw = 9 knot x-positions in VGPRs; tab = LDS row of
// (ch[k], dv[k]) pairs for this dim.
__device__ __forceinline__ void rqs_eval(float x, const float* __restrict__ cw,
                                         const v2f* __restrict__ tab,
                                         float& o, float& ld) {
    const float xi = __builtin_amdgcn_fmed3f(x, -TAILF, TAILF);  // clamp, 1 op
    float icw = cw[0], ncw = cw[1];
    int idx = 0;
#pragma unroll
    for (int k = 1; k < KBINS; ++k) {
        const bool c = xi >= cw[k];
        icw = c ? cw[k]     : icw;
        ncw = c ? cw[k + 1] : ncw;
        idx += c ? 1 : 0;
    }
    // gather (ich,dlo) and (nch,dhi) from LDS: 2x ds_read_b64, shared vaddr
    const v2f lo = tab[idx];
    const v2f hi = tab[idx + 1];
    const float ich = lo.x, dlo = lo.y;
    const float nch = hi.x, dhi = hi.y;

    const float iw  = ncw - icw;
    const float ih  = nch - ich;
    const float riw = rcp_fast(iw);
    const float delta = ih * riw;
    const float theta = (xi - icw) * riw;
    const float omt   = 1.0f - theta;
    const float t1m   = theta * omt;
    const float th2   = theta * theta;
    const float num   = ih * fmaf(delta, th2, dlo * t1m);
    const float den   = fmaf(dlo + dhi - 2.0f * delta, t1m, delta);
    const float rden  = rcp_fast(den);
    const float o_in  = fmaf(num, rden, ich);
    const float dn    = (delta * delta) *
                        fmaf(dhi, th2, fmaf(2.0f * delta, t1m, dlo * (omt * omt)));
    // log(dn) - 2 log(den) == log(dn * rden * rden): ONE fast log
    const float ld_in = __logf(dn * rden * rden);
    const bool inside = fabsf(x) <= TAILF;  // |x| is a free input modifier
    o  = inside ? o_in : x;
    ld = inside ? ld_in : 0.0f;
}

__global__ __launch_bounds__(BLOCK, 4)
void rqs_kernel(const float* __restrict__ inp,
                const float* __restrict__ params,
                float* __restrict__ out) {
    // (ch[k], dv[k]) pairs per local dim: 512 * 9 * 8 B = 36,864 B
    __shared__ v2f chdv[DIMS_PER_BLOCK][KBINS + 1];

    const int b        = blockIdx.x;
    const int colBlock = b & (BLOCKS_PER_ROW - 1);
    const int rowGroup = b / BLOCKS_PER_ROW;
    const int l0   = (int)threadIdx.x * VEC;          // local dim index
    const int d0   = colBlock * DIMS_PER_BLOCK + l0;  // global dim index
    const int row0 = rowGroup * ROWS_PER_WALK;

    const float edge_deriv = MIND + softplus_fast(__logf(__expf(1.0f - MIND) - 1.0f));

    float cw[VEC][KBINS + 1];
#pragma unroll
    for (int v = 0; v < VEC; ++v) {
        const float* __restrict__ p = params + (size_t)(d0 + v) * NPAR;
        // widths -> cw knots (stay in registers: needed by the compare chain)
        {
            float u[KBINS];
            float m = p[0];
#pragma unroll
            for (int k = 1; k < KBINS; ++k) m = fmaxf(m, p[k]);
            float s = 0.0f;
#pragma unroll
            for (int k = 0; k < KBINS; ++k) { u[k] = __expf(p[k] - m); s += u[k]; }
            const float scale = (1.0f - MINW * KBINS) * rcp_fast(s);
            cw[v][0] = -TAILF;
            float acc = 0.0f;
#pragma unroll
            for (int k = 0; k < KBINS - 1; ++k) {
                acc += MINW + scale * u[k];
                cw[v][k + 1] = fmaf(2.0f * TAILF, acc, -TAILF);
            }
            cw[v][KBINS] = TAILF;
        }
        // heights + derivatives -> LDS (ch[k], dv[k]) pairs
        {
            const float* __restrict__ q = p + KBINS;
            float u[KBINS];
            float m = q[0];
#pragma unroll
            for (int k = 1; k < KBINS; ++k) m = fmaxf(m, q[k]);
            float s = 0.0f;
#pragma unroll
            for (int k = 0; k < KBINS; ++k) { u[k] = __expf(q[k] - m); s += u[k]; }
            const float scale = (1.0f - MINH * KBINS) * rcp_fast(s);
            v2f e0; e0.x = -TAILF; e0.y = edge_deriv;
            chdv[l0 + v][0] = e0;
            float acc = 0.0f;
#pragma unroll
            for (int k = 0; k < KBINS; ++k) {
                acc += MINH + scale * u[k];
                v2f e;
                e.x = (k == KBINS - 1) ? TAILF
                                       : fmaf(2.0f * TAILF, acc, -TAILF);
                // interior knot k+1 uses params[2K + (k+1) - 1] = p[16 + k]
                e.y = (k == KBINS - 1) ? edge_deriv
                                       : MIND + softplus_fast(p[2 * KBINS + k]);
                chdv[l0 + v][k + 1] = e;
            }
        }
    }
    __syncthreads();

    const v2f* __restrict__ tab0 = &chdv[l0][0];
    const v2f* __restrict__ tab1 = &chdv[l0 + 1][0];

    const v2f* __restrict__ in2 = (const v2f*)inp;
    v2f* __restrict__ out2 = (v2f*)out;
    v2f* __restrict__ ld2  = (v2f*)(out + (size_t)NROWS * NDIM);

    size_t idx2 = ((size_t)row0 * NDIM + d0) >> 1;  // index in float2 units
#pragma unroll 4
    for (int r = 0; r < ROWS_PER_WALK; ++r) {
        const v2f xv = in2[idx2];
        float o0, ldv0, o1, ldv1;
        rqs_eval(xv.x, cw[0], tab0, o0, ldv0);
        rqs_eval(xv.y, cw[1], tab1, o1, ldv1);
        v2f ov; ov.x = o0; ov.y = o1;
        v2f lv; lv.x = ldv0; lv.y = ldv1;
        out2[idx2] = ov;
        ld2[idx2]  = lv;
        idx2 += NDIM / 2;
    }
}

extern "C" void kernel_launch(void* const* d_in, const int* in_sizes, int n_in,
                              void* d_out, int out_size, void* d_ws, size_t ws_size,
                              hipStream_t stream) {
    const float* inp    = (const float*)d_in[0];
    const float* params = (const float*)d_in[1];
    float* out          = (float*)d_out;
    rqs_kernel<<<BLOCKS_PER_ROW * GROWS, BLOCK, 0, stream>>>(inp, params, out);
}